// Round 8
// baseline (718.661 us; speedup 1.0000x reference)
//
#include <hip/hip_runtime.h>
#include <cstdint>
#include <type_traits>

typedef __attribute__((ext_vector_type(8))) short short8;
typedef __attribute__((ext_vector_type(4))) float floatx4;

#define NB 2
#define NS 2048
#define ND 2048
#define NH 16
#define NHD 128

__device__ __forceinline__ float b2f(short s) {
  unsigned u = ((unsigned)(unsigned short)s) << 16;
  return __builtin_bit_cast(float, u);
}
__device__ __forceinline__ short f2b(float f) {
  unsigned u = __builtin_bit_cast(unsigned, f);
  unsigned r = (u + 0x7fffu + ((u >> 16) & 1u)) >> 16;
  return (short)(unsigned short)r;
}

// ---------------- fused cast: x|wq|wk|wv|wo -> contiguous bf16 ws [xb|wqkvb|wob] -------
__global__ void cast_all(const float* __restrict__ x, const float* __restrict__ wq,
                         const float* __restrict__ wk, const float* __restrict__ wv,
                         const float* __restrict__ wo, short* __restrict__ dst) {
  const int i = blockIdx.x * blockDim.x + threadIdx.x;  // short4 units, block-uniform ranges
  const float* src;
  int off;
  if (i < 2097152) { src = x;  off = i; }
  else if (i < 3145728) { src = wq; off = i - 2097152; }
  else if (i < 4194304) { src = wk; off = i - 3145728; }
  else if (i < 5242880) { src = wv; off = i - 4194304; }
  else { src = wo; off = i - 5242880; }
  float4 v = ((const float4*)src)[off];
  short4 o;
  o.x = f2b(v.x); o.y = f2b(v.y); o.z = f2b(v.z); o.w = f2b(v.w);
  ((short4*)dst)[i] = o;
}

// ---------------- async global->LDS, 16B/lane ----------------
__device__ __forceinline__ void gld_lds16(const void* g, void* l) {
  __builtin_amdgcn_global_load_lds((const __attribute__((address_space(1))) void*)g,
                                   (__attribute__((address_space(3))) void*)l,
                                   16, 0, 0);
}

// ---------------- fused QKV GEMM, BK=64, XOR-swizzled LDS ----------------
// C = x (4096x2048) * Wqkv^T (6144x2048). col-block: 0-15 Q head-major, 16-31 K head-major,
// 32-47 V token-major. LDS[r][c] holds global chunk c^(r&7) (16B chunks, 8/row).
__global__ __launch_bounds__(256) void qkv_gemm(const short* __restrict__ A,
                                                const short* __restrict__ Bt,
                                                short* __restrict__ Qh,
                                                short* __restrict__ Kh,
                                                short* __restrict__ vlin) {
  constexpr int K = 2048;
  __shared__ short As[128 * 64];
  __shared__ short Bs[128 * 64];
  const int m0 = blockIdx.y * 128, n0 = blockIdx.x * 128;
  const int which = n0 >> 11;
  const int nl0 = n0 & 2047;
  const int t = threadIdx.x;
  const int wave = t >> 6, lane = t & 63, l15 = lane & 15, quad = lane >> 4;
  const int wm = (wave >> 1) * 64, wn = (wave & 1) * 64;

  floatx4 acc[4][4] = {};

  const int srow = t >> 3;                  // 0..31
  const int scol = (t & 7) ^ (srow & 7);    // swizzled global chunk for this lane
  const short* Ag = A + (long)(m0 + srow) * K + scol * 8;
  const short* Bg = Bt + (long)(n0 + srow) * K + scol * 8;
  char* AsB = (char*)As;
  char* BsB = (char*)Bs;
  const int ldsOff = wave * 1024;  // 8 rows x 128 B per wave

  for (int kt = 0; kt < K; kt += 64) {
#pragma unroll
    for (int i = 0; i < 4; ++i) {
      gld_lds16(Ag + kt + (long)(32 * i) * K, AsB + ldsOff + i * 4096);
      gld_lds16(Bg + kt + (long)(32 * i) * K, BsB + ldsOff + i * 4096);
    }
    __syncthreads();

#pragma unroll
    for (int half = 0; half < 2; ++half) {
      short8 a[4], b[4];
#pragma unroll
      for (int mi = 0; mi < 4; ++mi) {
        const int rr = wm + mi * 16 + l15;
        a[mi] = *(const short8*)&As[rr * 64 + (((half << 2) | quad) ^ (rr & 7)) * 8];
      }
#pragma unroll
      for (int ni = 0; ni < 4; ++ni) {
        const int rr = wn + ni * 16 + l15;
        b[ni] = *(const short8*)&Bs[rr * 64 + (((half << 2) | quad) ^ (rr & 7)) * 8];
      }
#pragma unroll
      for (int mi = 0; mi < 4; ++mi)
#pragma unroll
        for (int ni = 0; ni < 4; ++ni)
          acc[mi][ni] = __builtin_amdgcn_mfma_f32_16x16x32_bf16(a[mi], b[ni], acc[mi][ni], 0, 0, 0);
    }
    __syncthreads();
  }

  short* headDst = (which == 0) ? Qh : Kh;
#pragma unroll
  for (int mi = 0; mi < 4; ++mi) {
#pragma unroll
    for (int ni = 0; ni < 4; ++ni) {
#pragma unroll
      for (int r = 0; r < 4; ++r) {
        const int row = m0 + wm + mi * 16 + quad * 4 + r;
        const int col = nl0 + wn + ni * 16 + l15;
        const short v = f2b(acc[mi][ni][r]);
        if (which == 2) {
          vlin[(long)row * 2048 + col] = v;
        } else {
          const int bb = row >> 11, s = row & 2047, h = col >> 7, hd = col & 127;
          headDst[(((long)(bb * 16 + h) * 2048) + s) * 128 + hd] = v;
        }
      }
    }
  }
}

// ---------------- output GEMM: fp32 out, token-major; BK=64 swizzled ----------------
__global__ __launch_bounds__(256) void gemm_out(const short* __restrict__ A,
                                                const short* __restrict__ Bt,
                                                float* __restrict__ Cout) {
  constexpr int K = 2048, N = 2048;
  __shared__ short As[128 * 64];
  __shared__ short Bs[128 * 64];
  const int m0 = blockIdx.y * 128, n0 = blockIdx.x * 128;
  const int t = threadIdx.x;
  const int wave = t >> 6, lane = t & 63, l15 = lane & 15, quad = lane >> 4;
  const int wm = (wave >> 1) * 64, wn = (wave & 1) * 64;

  floatx4 acc[4][4] = {};

  const int srow = t >> 3;
  const int scol = (t & 7) ^ (srow & 7);
  const short* Ag = A + (long)(m0 + srow) * K + scol * 8;
  const short* Bg = Bt + (long)(n0 + srow) * K + scol * 8;
  char* AsB = (char*)As;
  char* BsB = (char*)Bs;
  const int ldsOff = wave * 1024;

  for (int kt = 0; kt < K; kt += 64) {
#pragma unroll
    for (int i = 0; i < 4; ++i) {
      gld_lds16(Ag + kt + (long)(32 * i) * K, AsB + ldsOff + i * 4096);
      gld_lds16(Bg + kt + (long)(32 * i) * K, BsB + ldsOff + i * 4096);
    }
    __syncthreads();

#pragma unroll
    for (int half = 0; half < 2; ++half) {
      short8 a[4], b[4];
#pragma unroll
      for (int mi = 0; mi < 4; ++mi) {
        const int rr = wm + mi * 16 + l15;
        a[mi] = *(const short8*)&As[rr * 64 + (((half << 2) | quad) ^ (rr & 7)) * 8];
      }
#pragma unroll
      for (int ni = 0; ni < 4; ++ni) {
        const int rr = wn + ni * 16 + l15;
        b[ni] = *(const short8*)&Bs[rr * 64 + (((half << 2) | quad) ^ (rr & 7)) * 8];
      }
#pragma unroll
      for (int mi = 0; mi < 4; ++mi)
#pragma unroll
        for (int ni = 0; ni < 4; ++ni)
          acc[mi][ni] = __builtin_amdgcn_mfma_f32_16x16x32_bf16(a[mi], b[ni], acc[mi][ni], 0, 0, 0);
    }
    __syncthreads();
  }

#pragma unroll
  for (int mi = 0; mi < 4; ++mi)
#pragma unroll
    for (int ni = 0; ni < 4; ++ni)
#pragma unroll
      for (int r = 0; r < 4; ++r) {
        const int row = m0 + wm + mi * 16 + quad * 4 + r;
        const int col = n0 + wn + ni * 16 + l15;
        Cout[(long)row * N + col] = acc[mi][ni][r];
      }
}

// ------------- merged RoPE (blocks 0..4095) + V transpose (blocks 4096..6143) -------------
__global__ __launch_bounds__(256) void rope_vtrans(short* __restrict__ Qh,
                                                   short* __restrict__ Kh,
                                                   const float* __restrict__ pos,
                                                   const short* __restrict__ v_lin,
                                                   short* __restrict__ Vt) {
  __shared__ short tile[64 * 72];
  const int bx = blockIdx.x;
  if (bx < 4096) {
    // ---- RoPE in-place on head-major Q,K: 4096 blocks x 256 = token(4096) x h(16) x kk(16)
    const int tid = bx * 256 + threadIdx.x;
    const int kk = tid & 15;
    const int h = (tid >> 4) & 15;
    const int token = tid >> 8;
    const int bb = token >> 11, s = token & 2047;
    const float4 p4 = ((const float4*)pos)[token];
    const float pv[4] = {p4.x, p4.y, p4.z, p4.w};
    const float theta = exp2f(-(float)kk * 0.8304820237218406f);
    const long base = (((long)(bb * 16 + h)) * 2048 + s) * 128 + kk * 8;
    short8 q8 = *(short8*)(Qh + base);
    short8 k8 = *(short8*)(Kh + base);
    short8 qo, ko;
#pragma unroll
    for (int jj = 0; jj < 4; ++jj) {
      const float fr = pv[jj] * theta;
      float sn, c;
      __sincosf(fr, &sn, &c);
      {
        const float tr = b2f(q8[2 * jj]), ti = b2f(q8[2 * jj + 1]);
        qo[2 * jj] = f2b(tr * c - ti * sn);
        qo[2 * jj + 1] = f2b(tr * sn + ti * c);
      }
      {
        const float tr = b2f(k8[2 * jj]), ti = b2f(k8[2 * jj + 1]);
        ko[2 * jj] = f2b(tr * c - ti * sn);
        ko[2 * jj + 1] = f2b(tr * sn + ti * c);
      }
    }
    *(short8*)(Qh + base) = qo;
    *(short8*)(Kh + base) = ko;
  } else {
    // ---- V transpose: vlin [token][h*128+hd] -> Vt [b][h][hd][s] ----
    const int b2 = bx - 4096;  // 0..2047
    const int s0 = (b2 & 31) * 64;
    const int hd0 = ((b2 >> 5) & 1) * 64;
    const int bh = b2 >> 6;
    const int bb = bh >> 4, h = bh & 15;
    const int t = threadIdx.x;
#pragma unroll
    for (int i = 0; i < 2; ++i) {
      const int ch = t + i * 256;
      const int r = ch >> 3, c = ch & 7;
      *(short8*)&tile[r * 72 + c * 8] =
          *(const short8*)(v_lin + (long)(bb * 2048 + s0 + r) * 2048 + h * 128 + hd0 + c * 8);
    }
    __syncthreads();
#pragma unroll
    for (int i = 0; i < 2; ++i) {
      const int ch = t + i * 256;
      const int r2 = ch >> 3, c2 = ch & 7;
      short8 o;
#pragma unroll
      for (int u = 0; u < 8; ++u) o[u] = tile[(c2 * 8 + u) * 72 + r2];
      *(short8*)(Vt + ((long)(bh * 128 + hd0 + r2)) * 2048 + s0 + c2 * 8) = o;
    }
  }
}

// ---------------- flash attention, mirror-paired q-tiles, no-max softmax ----------------
// LDS 52 KB -> 3 blocks/CU. block (a,bh): q-row-blocks a*64 (rb=0) and (31-a)*64 (rb=1).
__global__ __launch_bounds__(256, 3) void flash(const short* __restrict__ Qh,
                                                const short* __restrict__ Kh,
                                                const short* __restrict__ Vt,
                                                short* __restrict__ ao) {
  __shared__ short Ks[64 * 136];    // 17408 B
  __shared__ short Vts[128 * 68];   // 17408 B
  __shared__ short Ps[4 * 32 * 72]; // 18432 B
  const int a = blockIdx.x;  // 0..15
  const int bh = blockIdx.y;
  const int t = threadIdx.x, wave = t >> 6, lane = t & 63, l15 = lane & 15, quad = lane >> 4;
  const int sqb[2] = {a * 64, (31 - a) * 64};
  const int lastkt0 = a, lastkt1 = 31 - a;

  const short* Qbase = Qh + (long)bh * 2048 * 128;
  short8 aq[2][4];
#pragma unroll
  for (int rb = 0; rb < 2; ++rb)
#pragma unroll
    for (int ks = 0; ks < 4; ++ks)
      aq[rb][ks] = *(const short8*)(Qbase + (long)(sqb[rb] + wave * 16 + l15) * 128 + ks * 32 + quad * 8);

  const short* KgBase = Kh + (long)bh * 2048 * 128;
  const short* VgBase = Vt + (long)bh * 128 * 2048;

  short8 kreg[4], vreg[4];
#pragma unroll
  for (int i = 0; i < 4; ++i) {
    const int ch = t + i * 256;
    kreg[i] = *(const short8*)(KgBase + (long)(ch >> 4) * 128 + (ch & 15) * 8);
    vreg[i] = *(const short8*)(VgBase + (long)(ch >> 3) * 2048 + (ch & 7) * 8);
  }

  float l_part[2][4] = {};
  floatx4 acc_o[2][8] = {};
  const float CEXP = 0.12751745f;  // (1/sqrt(128)) * log2(e)

  for (int kt = 0; kt <= lastkt1; ++kt) {
    const int k0 = kt * 64;
    if (kt > 0) __syncthreads();

#pragma unroll
    for (int i = 0; i < 4; ++i) {
      const int ch = t + i * 256;
      *(short8*)&Ks[(ch >> 4) * 136 + (ch & 15) * 8] = kreg[i];
      *(short8*)&Vts[(ch >> 3) * 68 + (ch & 7) * 8] = vreg[i];
    }
    __syncthreads();

    if (kt < lastkt1) {
      const short* Kg = KgBase + (long)(k0 + 64) * 128;
      const short* Vg = VgBase + (k0 + 64);
#pragma unroll
      for (int i = 0; i < 4; ++i) {
        const int ch = t + i * 256;
        kreg[i] = *(const short8*)(Kg + (long)(ch >> 4) * 128 + (ch & 15) * 8);
        vreg[i] = *(const short8*)(Vg + (long)(ch >> 3) * 2048 + (ch & 7) * 8);
      }
    }

    const bool dgf[2] = {kt == lastkt0, kt == lastkt1};

    auto step = [&](auto DO0C) {
      constexpr bool DO0 = decltype(DO0C)::value;
      floatx4 accs[2][4] = {};
#pragma unroll
      for (int ks = 0; ks < 4; ++ks) {
#pragma unroll
        for (int ni = 0; ni < 4; ++ni) {
          const short8 bk = *(const short8*)&Ks[(ni * 16 + l15) * 136 + ks * 32 + quad * 8];
          accs[1][ni] = __builtin_amdgcn_mfma_f32_16x16x32_bf16(aq[1][ks], bk, accs[1][ni], 0, 0, 0);
          if (DO0)
            accs[0][ni] = __builtin_amdgcn_mfma_f32_16x16x32_bf16(aq[0][ks], bk, accs[0][ni], 0, 0, 0);
        }
      }
#pragma unroll
      for (int rb = 0; rb < 2; ++rb) {
        if (rb == 0 && !DO0) continue;
        const bool dg = dgf[rb];
#pragma unroll
        for (int r = 0; r < 4; ++r) {
          const int qrow = sqb[rb] + wave * 16 + quad * 4 + r;
#pragma unroll
          for (int ni = 0; ni < 4; ++ni) {
            float e = exp2f(accs[rb][ni][r] * CEXP);
            if (dg && (k0 + ni * 16 + l15) > qrow) e = 0.f;
            Ps[wave * 2304 + (rb * 16 + quad * 4 + r) * 72 + ni * 16 + l15] = f2b(e);
            l_part[rb][r] += e;
          }
        }
      }
#pragma unroll
      for (int ks2 = 0; ks2 < 2; ++ks2) {
        short8 ap1 = *(const short8*)&Ps[wave * 2304 + (16 + l15) * 72 + ks2 * 32 + quad * 8];
        short8 ap0;
        if (DO0) ap0 = *(const short8*)&Ps[wave * 2304 + l15 * 72 + ks2 * 32 + quad * 8];
#pragma unroll
        for (int nh = 0; nh < 8; ++nh) {
          const short8 bv = *(const short8*)&Vts[(nh * 16 + l15) * 68 + ks2 * 32 + quad * 8];
          acc_o[1][nh] = __builtin_amdgcn_mfma_f32_16x16x32_bf16(ap1, bv, acc_o[1][nh], 0, 0, 0);
          if (DO0)
            acc_o[0][nh] = __builtin_amdgcn_mfma_f32_16x16x32_bf16(ap0, bv, acc_o[0][nh], 0, 0, 0);
        }
      }
    };

    if (kt <= lastkt0)
      step(std::integral_constant<bool, true>{});
    else
      step(std::integral_constant<bool, false>{});
  }

  const int bb = bh >> 4, h = bh & 15;
#pragma unroll
  for (int rb = 0; rb < 2; ++rb) {
#pragma unroll
    for (int r = 0; r < 4; ++r) {
      float rs = l_part[rb][r];
#pragma unroll
      for (int mm = 8; mm >= 1; mm >>= 1) rs += __shfl_xor(rs, mm, 16);
      const float inv = 1.0f / rs;
      const int s = sqb[rb] + wave * 16 + quad * 4 + r;
      const long rowbase = ((long)(bb * 2048 + s)) * 2048 + h * 128;
#pragma unroll
      for (int nh = 0; nh < 8; ++nh) ao[rowbase + nh * 16 + l15] = f2b(acc_o[rb][nh][r] * inv);
    }
  }
}

extern "C" void kernel_launch(void* const* d_in, const int* in_sizes, int n_in,
                              void* d_out, int out_size, void* d_ws, size_t ws_size,
                              hipStream_t stream) {
  const float* x = (const float*)d_in[0];
  const float* pos = (const float*)d_in[1];
  const float* wq = (const float*)d_in[3];
  const float* wk = (const float*)d_in[4];
  const float* wv = (const float*)d_in[5];
  const float* wo = (const float*)d_in[6];
  float* out = (float*)d_out;

  char* ws = (char*)d_ws;
  const size_t MB = 1024 * 1024;
  short* xb    = (short*)(ws + 0);        // 16 MB
  short* wqkvb = (short*)(ws + 16 * MB);  // 24 MB
  short* wob   = (short*)(ws + 40 * MB);  // 8 MB
  short* Qh    = (short*)(ws + 48 * MB);  // 16 MB
  short* Kh    = (short*)(ws + 64 * MB);  // 16 MB
  short* Vt    = (short*)(ws + 80 * MB);  // 16 MB
  short* vlin  = (short*)(ws + 96 * MB);  // 16 MB
  short* ao    = (short*)(ws + 96 * MB);  // alias vlin (vtrans consumes vlin before flash)
  // total 112 MB

  cast_all<<<24576, 256, 0, stream>>>(x, wq, wk, wv, wo, xb);

  qkv_gemm<<<dim3(48, 32), 256, 0, stream>>>(xb, wqkvb, Qh, Kh, vlin);

  rope_vtrans<<<6144, 256, 0, stream>>>(Qh, Kh, pos, vlin, Vt);

  flash<<<dim3(16, 32), 256, 0, stream>>>(Qh, Kh, Vt, ao);

  gemm_out<<<dim3(16, 32), 256, 0, stream>>>(ao, wob, out);
}

// Round 9
// 414.425 us; speedup vs baseline: 1.7341x; 1.7341x over previous
//
#include <hip/hip_runtime.h>
#include <cstdint>
#include <type_traits>

typedef __attribute__((ext_vector_type(8))) short short8;
typedef __attribute__((ext_vector_type(4))) float floatx4;

#define NB 2
#define NS 2048
#define ND 2048
#define NH 16
#define NHD 128

__device__ __forceinline__ float b2f(short s) {
  unsigned u = ((unsigned)(unsigned short)s) << 16;
  return __builtin_bit_cast(float, u);
}
__device__ __forceinline__ short f2b(float f) {
  unsigned u = __builtin_bit_cast(unsigned, f);
  unsigned r = (u + 0x7fffu + ((u >> 16) & 1u)) >> 16;
  return (short)(unsigned short)r;
}

// ---------------- fused cast: x|wq|wk|wv|wo -> contiguous bf16 ws [xb|wqkvb|wob] -------
__global__ void cast_all(const float* __restrict__ x, const float* __restrict__ wq,
                         const float* __restrict__ wk, const float* __restrict__ wv,
                         const float* __restrict__ wo, short* __restrict__ dst) {
  const int i = blockIdx.x * blockDim.x + threadIdx.x;  // short4 units, block-uniform ranges
  const float* src;
  int off;
  if (i < 2097152) { src = x;  off = i; }
  else if (i < 3145728) { src = wq; off = i - 2097152; }
  else if (i < 4194304) { src = wk; off = i - 3145728; }
  else if (i < 5242880) { src = wv; off = i - 4194304; }
  else { src = wo; off = i - 5242880; }
  float4 v = ((const float4*)src)[off];
  short4 o;
  o.x = f2b(v.x); o.y = f2b(v.y); o.z = f2b(v.z); o.w = f2b(v.w);
  ((short4*)dst)[i] = o;
}

// ---------------- async global->LDS, 16B/lane ----------------
__device__ __forceinline__ void gld_lds16(const void* g, void* l) {
  __builtin_amdgcn_global_load_lds((const __attribute__((address_space(1))) void*)g,
                                   (__attribute__((address_space(3))) void*)l,
                                   16, 0, 0);
}

// ---------------- fused QKV GEMM, BK=64, XOR-swizzled LDS ----------------
// C = x (4096x2048) * Wqkv^T (6144x2048). col-block: 0-15 Q head-major, 16-31 K head-major,
// 32-47 V token-major. LDS[r][c] holds global chunk c^(r&7) (16B chunks, 8/row).
__global__ __launch_bounds__(256) void qkv_gemm(const short* __restrict__ A,
                                                const short* __restrict__ Bt,
                                                short* __restrict__ Qh,
                                                short* __restrict__ Kh,
                                                short* __restrict__ vlin) {
  constexpr int K = 2048;
  __shared__ short As[128 * 64];
  __shared__ short Bs[128 * 64];
  const int m0 = blockIdx.y * 128, n0 = blockIdx.x * 128;
  const int which = n0 >> 11;
  const int nl0 = n0 & 2047;
  const int t = threadIdx.x;
  const int wave = t >> 6, lane = t & 63, l15 = lane & 15, quad = lane >> 4;
  const int wm = (wave >> 1) * 64, wn = (wave & 1) * 64;

  floatx4 acc[4][4] = {};

  const int srow = t >> 3;                  // 0..31
  const int scol = (t & 7) ^ (srow & 7);    // swizzled global chunk for this lane
  const short* Ag = A + (long)(m0 + srow) * K + scol * 8;
  const short* Bg = Bt + (long)(n0 + srow) * K + scol * 8;
  char* AsB = (char*)As;
  char* BsB = (char*)Bs;
  const int ldsOff = wave * 1024;  // 8 rows x 128 B per wave

  for (int kt = 0; kt < K; kt += 64) {
#pragma unroll
    for (int i = 0; i < 4; ++i) {
      gld_lds16(Ag + kt + (long)(32 * i) * K, AsB + ldsOff + i * 4096);
      gld_lds16(Bg + kt + (long)(32 * i) * K, BsB + ldsOff + i * 4096);
    }
    __syncthreads();

#pragma unroll
    for (int half = 0; half < 2; ++half) {
      short8 a[4], b[4];
#pragma unroll
      for (int mi = 0; mi < 4; ++mi) {
        const int rr = wm + mi * 16 + l15;
        a[mi] = *(const short8*)&As[rr * 64 + (((half << 2) | quad) ^ (rr & 7)) * 8];
      }
#pragma unroll
      for (int ni = 0; ni < 4; ++ni) {
        const int rr = wn + ni * 16 + l15;
        b[ni] = *(const short8*)&Bs[rr * 64 + (((half << 2) | quad) ^ (rr & 7)) * 8];
      }
#pragma unroll
      for (int mi = 0; mi < 4; ++mi)
#pragma unroll
        for (int ni = 0; ni < 4; ++ni)
          acc[mi][ni] = __builtin_amdgcn_mfma_f32_16x16x32_bf16(a[mi], b[ni], acc[mi][ni], 0, 0, 0);
    }
    __syncthreads();
  }

  short* headDst = (which == 0) ? Qh : Kh;
#pragma unroll
  for (int mi = 0; mi < 4; ++mi) {
#pragma unroll
    for (int ni = 0; ni < 4; ++ni) {
#pragma unroll
      for (int r = 0; r < 4; ++r) {
        const int row = m0 + wm + mi * 16 + quad * 4 + r;
        const int col = nl0 + wn + ni * 16 + l15;
        const short v = f2b(acc[mi][ni][r]);
        if (which == 2) {
          vlin[(long)row * 2048 + col] = v;
        } else {
          const int bb = row >> 11, s = row & 2047, h = col >> 7, hd = col & 127;
          headDst[(((long)(bb * 16 + h) * 2048) + s) * 128 + hd] = v;
        }
      }
    }
  }
}

// ---------------- output GEMM: fp32 out, token-major; BK=64 swizzled ----------------
__global__ __launch_bounds__(256) void gemm_out(const short* __restrict__ A,
                                                const short* __restrict__ Bt,
                                                float* __restrict__ Cout) {
  constexpr int K = 2048, N = 2048;
  __shared__ short As[128 * 64];
  __shared__ short Bs[128 * 64];
  const int m0 = blockIdx.y * 128, n0 = blockIdx.x * 128;
  const int t = threadIdx.x;
  const int wave = t >> 6, lane = t & 63, l15 = lane & 15, quad = lane >> 4;
  const int wm = (wave >> 1) * 64, wn = (wave & 1) * 64;

  floatx4 acc[4][4] = {};

  const int srow = t >> 3;
  const int scol = (t & 7) ^ (srow & 7);
  const short* Ag = A + (long)(m0 + srow) * K + scol * 8;
  const short* Bg = Bt + (long)(n0 + srow) * K + scol * 8;
  char* AsB = (char*)As;
  char* BsB = (char*)Bs;
  const int ldsOff = wave * 1024;

  for (int kt = 0; kt < K; kt += 64) {
#pragma unroll
    for (int i = 0; i < 4; ++i) {
      gld_lds16(Ag + kt + (long)(32 * i) * K, AsB + ldsOff + i * 4096);
      gld_lds16(Bg + kt + (long)(32 * i) * K, BsB + ldsOff + i * 4096);
    }
    __syncthreads();

#pragma unroll
    for (int half = 0; half < 2; ++half) {
      short8 a[4], b[4];
#pragma unroll
      for (int mi = 0; mi < 4; ++mi) {
        const int rr = wm + mi * 16 + l15;
        a[mi] = *(const short8*)&As[rr * 64 + (((half << 2) | quad) ^ (rr & 7)) * 8];
      }
#pragma unroll
      for (int ni = 0; ni < 4; ++ni) {
        const int rr = wn + ni * 16 + l15;
        b[ni] = *(const short8*)&Bs[rr * 64 + (((half << 2) | quad) ^ (rr & 7)) * 8];
      }
#pragma unroll
      for (int mi = 0; mi < 4; ++mi)
#pragma unroll
        for (int ni = 0; ni < 4; ++ni)
          acc[mi][ni] = __builtin_amdgcn_mfma_f32_16x16x32_bf16(a[mi], b[ni], acc[mi][ni], 0, 0, 0);
    }
    __syncthreads();
  }

#pragma unroll
  for (int mi = 0; mi < 4; ++mi)
#pragma unroll
    for (int ni = 0; ni < 4; ++ni)
#pragma unroll
      for (int r = 0; r < 4; ++r) {
        const int row = m0 + wm + mi * 16 + quad * 4 + r;
        const int col = n0 + wn + ni * 16 + l15;
        Cout[(long)row * N + col] = acc[mi][ni][r];
      }
}

// ------------- merged RoPE (blocks 0..4095) + V transpose (blocks 4096..6143) -------------
__global__ __launch_bounds__(256) void rope_vtrans(short* __restrict__ Qh,
                                                   short* __restrict__ Kh,
                                                   const float* __restrict__ pos,
                                                   const short* __restrict__ v_lin,
                                                   short* __restrict__ Vt) {
  __shared__ short tile[64 * 72];
  const int bx = blockIdx.x;
  if (bx < 4096) {
    // ---- RoPE in-place on head-major Q,K: 4096 blocks x 256 = token(4096) x h(16) x kk(16)
    const int tid = bx * 256 + threadIdx.x;
    const int kk = tid & 15;
    const int h = (tid >> 4) & 15;
    const int token = tid >> 8;
    const int bb = token >> 11, s = token & 2047;
    const float4 p4 = ((const float4*)pos)[token];
    const float pv[4] = {p4.x, p4.y, p4.z, p4.w};
    const float theta = exp2f(-(float)kk * 0.8304820237218406f);
    const long base = (((long)(bb * 16 + h)) * 2048 + s) * 128 + kk * 8;
    short8 q8 = *(short8*)(Qh + base);
    short8 k8 = *(short8*)(Kh + base);
    short8 qo, ko;
#pragma unroll
    for (int jj = 0; jj < 4; ++jj) {
      const float fr = pv[jj] * theta;
      float sn, c;
      __sincosf(fr, &sn, &c);
      {
        const float tr = b2f(q8[2 * jj]), ti = b2f(q8[2 * jj + 1]);
        qo[2 * jj] = f2b(tr * c - ti * sn);
        qo[2 * jj + 1] = f2b(tr * sn + ti * c);
      }
      {
        const float tr = b2f(k8[2 * jj]), ti = b2f(k8[2 * jj + 1]);
        ko[2 * jj] = f2b(tr * c - ti * sn);
        ko[2 * jj + 1] = f2b(tr * sn + ti * c);
      }
    }
    *(short8*)(Qh + base) = qo;
    *(short8*)(Kh + base) = ko;
  } else {
    // ---- V transpose: vlin [token][h*128+hd] -> Vt [b][h][hd][s] ----
    const int b2 = bx - 4096;  // 0..2047
    const int s0 = (b2 & 31) * 64;
    const int hd0 = ((b2 >> 5) & 1) * 64;
    const int bh = b2 >> 6;
    const int bb = bh >> 4, h = bh & 15;
    const int t = threadIdx.x;
#pragma unroll
    for (int i = 0; i < 2; ++i) {
      const int ch = t + i * 256;
      const int r = ch >> 3, c = ch & 7;
      *(short8*)&tile[r * 72 + c * 8] =
          *(const short8*)(v_lin + (long)(bb * 2048 + s0 + r) * 2048 + h * 128 + hd0 + c * 8);
    }
    __syncthreads();
#pragma unroll
    for (int i = 0; i < 2; ++i) {
      const int ch = t + i * 256;
      const int r2 = ch >> 3, c2 = ch & 7;
      short8 o;
#pragma unroll
      for (int u = 0; u < 8; ++u) o[u] = tile[(c2 * 8 + u) * 72 + r2];
      *(short8*)(Vt + ((long)(bh * 128 + hd0 + r2)) * 2048 + s0 + c2 * 8) = o;
    }
  }
}

// ---------------- flash attention, mirror-paired q-tiles, no-max softmax ----------------
// 2 blocks/CU: live state ~180 regs/lane, (256,3) spills to scratch (R8: 738 MB WRITE_SIZE).
__global__ __launch_bounds__(256, 2) void flash(const short* __restrict__ Qh,
                                                const short* __restrict__ Kh,
                                                const short* __restrict__ Vt,
                                                short* __restrict__ ao) {
  __shared__ short Ks[64 * 136];    // 17408 B
  __shared__ short Vts[128 * 68];   // 17408 B
  __shared__ short Ps[4 * 32 * 72]; // 18432 B
  const int a = blockIdx.x;  // 0..15
  const int bh = blockIdx.y;
  const int t = threadIdx.x, wave = t >> 6, lane = t & 63, l15 = lane & 15, quad = lane >> 4;
  const int sqb[2] = {a * 64, (31 - a) * 64};
  const int lastkt0 = a, lastkt1 = 31 - a;

  const short* Qbase = Qh + (long)bh * 2048 * 128;
  short8 aq[2][4];
#pragma unroll
  for (int rb = 0; rb < 2; ++rb)
#pragma unroll
    for (int ks = 0; ks < 4; ++ks)
      aq[rb][ks] = *(const short8*)(Qbase + (long)(sqb[rb] + wave * 16 + l15) * 128 + ks * 32 + quad * 8);

  const short* KgBase = Kh + (long)bh * 2048 * 128;
  const short* VgBase = Vt + (long)bh * 128 * 2048;

  short8 kreg[4], vreg[4];
#pragma unroll
  for (int i = 0; i < 4; ++i) {
    const int ch = t + i * 256;
    kreg[i] = *(const short8*)(KgBase + (long)(ch >> 4) * 128 + (ch & 15) * 8);
    vreg[i] = *(const short8*)(VgBase + (long)(ch >> 3) * 2048 + (ch & 7) * 8);
  }

  float l_part[2][4] = {};
  floatx4 acc_o[2][8] = {};
  const float CEXP = 0.12751745f;  // (1/sqrt(128)) * log2(e)

  for (int kt = 0; kt <= lastkt1; ++kt) {
    const int k0 = kt * 64;
    if (kt > 0) __syncthreads();

#pragma unroll
    for (int i = 0; i < 4; ++i) {
      const int ch = t + i * 256;
      *(short8*)&Ks[(ch >> 4) * 136 + (ch & 15) * 8] = kreg[i];
      *(short8*)&Vts[(ch >> 3) * 68 + (ch & 7) * 8] = vreg[i];
    }
    __syncthreads();

    if (kt < lastkt1) {
      const short* Kg = KgBase + (long)(k0 + 64) * 128;
      const short* Vg = VgBase + (k0 + 64);
#pragma unroll
      for (int i = 0; i < 4; ++i) {
        const int ch = t + i * 256;
        kreg[i] = *(const short8*)(Kg + (long)(ch >> 4) * 128 + (ch & 15) * 8);
        vreg[i] = *(const short8*)(Vg + (long)(ch >> 3) * 2048 + (ch & 7) * 8);
      }
    }

    const bool dgf[2] = {kt == lastkt0, kt == lastkt1};

    auto step = [&](auto DO0C) {
      constexpr bool DO0 = decltype(DO0C)::value;
      floatx4 accs[2][4] = {};
#pragma unroll
      for (int ks = 0; ks < 4; ++ks) {
#pragma unroll
        for (int ni = 0; ni < 4; ++ni) {
          const short8 bk = *(const short8*)&Ks[(ni * 16 + l15) * 136 + ks * 32 + quad * 8];
          accs[1][ni] = __builtin_amdgcn_mfma_f32_16x16x32_bf16(aq[1][ks], bk, accs[1][ni], 0, 0, 0);
          if (DO0)
            accs[0][ni] = __builtin_amdgcn_mfma_f32_16x16x32_bf16(aq[0][ks], bk, accs[0][ni], 0, 0, 0);
        }
      }
#pragma unroll
      for (int rb = 0; rb < 2; ++rb) {
        if (rb == 0 && !DO0) continue;
        const bool dg = dgf[rb];
#pragma unroll
        for (int r = 0; r < 4; ++r) {
          const int qrow = sqb[rb] + wave * 16 + quad * 4 + r;
#pragma unroll
          for (int ni = 0; ni < 4; ++ni) {
            float e = exp2f(accs[rb][ni][r] * CEXP);
            if (dg && (k0 + ni * 16 + l15) > qrow) e = 0.f;
            Ps[wave * 2304 + (rb * 16 + quad * 4 + r) * 72 + ni * 16 + l15] = f2b(e);
            l_part[rb][r] += e;
          }
        }
      }
#pragma unroll
      for (int ks2 = 0; ks2 < 2; ++ks2) {
        short8 ap1 = *(const short8*)&Ps[wave * 2304 + (16 + l15) * 72 + ks2 * 32 + quad * 8];
        short8 ap0;
        if (DO0) ap0 = *(const short8*)&Ps[wave * 2304 + l15 * 72 + ks2 * 32 + quad * 8];
#pragma unroll
        for (int nh = 0; nh < 8; ++nh) {
          const short8 bv = *(const short8*)&Vts[(nh * 16 + l15) * 68 + ks2 * 32 + quad * 8];
          acc_o[1][nh] = __builtin_amdgcn_mfma_f32_16x16x32_bf16(ap1, bv, acc_o[1][nh], 0, 0, 0);
          if (DO0)
            acc_o[0][nh] = __builtin_amdgcn_mfma_f32_16x16x32_bf16(ap0, bv, acc_o[0][nh], 0, 0, 0);
        }
      }
    };

    if (kt <= lastkt0)
      step(std::integral_constant<bool, true>{});
    else
      step(std::integral_constant<bool, false>{});
  }

  const int bb = bh >> 4, h = bh & 15;
#pragma unroll
  for (int rb = 0; rb < 2; ++rb) {
#pragma unroll
    for (int r = 0; r < 4; ++r) {
      float rs = l_part[rb][r];
#pragma unroll
      for (int mm = 8; mm >= 1; mm >>= 1) rs += __shfl_xor(rs, mm, 16);
      const float inv = 1.0f / rs;
      const int s = sqb[rb] + wave * 16 + quad * 4 + r;
      const long rowbase = ((long)(bb * 2048 + s)) * 2048 + h * 128;
#pragma unroll
      for (int nh = 0; nh < 8; ++nh) ao[rowbase + nh * 16 + l15] = f2b(acc_o[rb][nh][r] * inv);
    }
  }
}

extern "C" void kernel_launch(void* const* d_in, const int* in_sizes, int n_in,
                              void* d_out, int out_size, void* d_ws, size_t ws_size,
                              hipStream_t stream) {
  const float* x = (const float*)d_in[0];
  const float* pos = (const float*)d_in[1];
  const float* wq = (const float*)d_in[3];
  const float* wk = (const float*)d_in[4];
  const float* wv = (const float*)d_in[5];
  const float* wo = (const float*)d_in[6];
  float* out = (float*)d_out;

  char* ws = (char*)d_ws;
  const size_t MB = 1024 * 1024;
  short* xb    = (short*)(ws + 0);        // 16 MB
  short* wqkvb = (short*)(ws + 16 * MB);  // 24 MB
  short* wob   = (short*)(ws + 40 * MB);  // 8 MB
  short* Qh    = (short*)(ws + 48 * MB);  // 16 MB
  short* Kh    = (short*)(ws + 64 * MB);  // 16 MB
  short* Vt    = (short*)(ws + 80 * MB);  // 16 MB
  short* vlin  = (short*)(ws + 96 * MB);  // 16 MB
  short* ao    = (short*)(ws + 96 * MB);  // alias vlin (vtrans consumes vlin before flash)
  // total 112 MB

  cast_all<<<24576, 256, 0, stream>>>(x, wq, wk, wv, wo, xb);

  qkv_gemm<<<dim3(48, 32), 256, 0, stream>>>(xb, wqkvb, Qh, Kh, vlin);

  rope_vtrans<<<6144, 256, 0, stream>>>(Qh, Kh, pos, vlin, Vt);

  flash<<<dim3(16, 32), 256, 0, stream>>>(Qh, Kh, Vt, ao);

  gemm_out<<<dim3(16, 32), 256, 0, stream>>>(ao, wob, out);
}